// Round 18
// baseline (101.202 us; speedup 1.0000x reference)
//
#include <hip/hip_runtime.h>
#include <hip/hip_bf16.h>

// Problem constants (match reference)
#define NN 1024
#define FF 256
#define DD 64
#define RR 11
#define EE 2048
#define ALPHA 0.2f
#define TPB 512
#define EPT (EE / TPB)          // 4 edges per thread in K1
#define TILE_E 32               // edges per K2 tile (same relation)
#define PERM_CAP 2432           // >= 2048 + 11*31, = 76*32
#define K2_GRID (PERM_CAP / TILE_E)  // 76

// ws layout (bytes):
//   0     : int perm[PERM_CAP]   (9728 B)
//   12288 : int tile_rel[K2_GRID] (304 B)  relation per tile, -1 = empty
//   16384 : float cbuf[EE*FF]    (2 MB, e-major: cbuf[e*FF+f])

// K1: blocks 0..255 own feature f=(b&7)*32+(b>>3) [XCD-grouped]. Stage
//     x[:,f] in LDS; p/q wave-dots; single-pass softmax (|v|<~2);
//     c[e,f]=exp(v)*xd/sum (e-major). Block 256: relation counting-sort
//     into 32-padded buckets + tile_rel table (concurrent, no straggler).
__global__ __launch_bounds__(TPB) void k1_coef(
    const float* __restrict__ x, const float* __restrict__ W,
    const float* __restrict__ a, const int* __restrict__ src,
    const int* __restrict__ dst, const int* __restrict__ rel,
    float* __restrict__ cbuf, int* __restrict__ perm,
    int* __restrict__ tile_rel) {

    const int b    = blockIdx.x;   // 0..256
    const int tid  = threadIdx.x;  // 0..511
    const int wid  = tid >> 6;     // 0..7
    const int lane = tid & 63;

    __shared__ int hist[16], base_sh[16], off_sh[16];

    if (b == FF) {
        // dedicated sort block
        if (tid < 16) hist[tid] = 0;
        __syncthreads();
        for (int e = tid; e < EE; e += TPB) atomicAdd(&hist[rel[e]], 1);
        __syncthreads();
        if (tid == 0) {
            int acc = 0;
            for (int r = 0; r < RR; ++r) {
                base_sh[r] = acc;
                off_sh[r] = acc;
                acc += (hist[r] + TILE_E - 1) & ~(TILE_E - 1);
            }
            // tile -> relation table (-1 past the last bucket)
            int r = 0;
            for (int t = 0; t < K2_GRID; ++t) {
                while (r < RR && t * TILE_E >=
                       base_sh[r] + ((hist[r] + TILE_E - 1) & ~(TILE_E - 1)))
                    ++r;
                tile_rel[t] = (r < RR &&
                               t * TILE_E < base_sh[r] +
                               ((hist[r] + TILE_E - 1) & ~(TILE_E - 1)))
                              ? r : -1;
            }
        }
        __syncthreads();
        for (int i = tid; i < PERM_CAP; i += TPB) perm[i] = -1;
        __syncthreads();
        for (int e = tid; e < EE; e += TPB) {
            int pos = atomicAdd(&off_sh[rel[e]], 1);
            perm[pos] = e;
        }
        return;
    }

    const int f = ((b & 7) << 5) | (b >> 3);   // XCD-grouped feature

    __shared__ float xcol[NN];     // 4 KB: x[:, f]
    __shared__ float p_sh[RR], q_sh[RR];
    __shared__ float red_s[8];

    // hoist edge indices to kernel entry: 12 independent loads in flight
    int siA[EPT], diA[EPT], rA[EPT];
    #pragma unroll
    for (int k = 0; k < EPT; ++k) {
        int e = tid + k * TPB;
        siA[k] = src[e]; diA[k] = dst[e]; rA[k] = rel[e];
    }

    // stage column f of x (lines L2-shared within this XCD)
    for (int i = tid; i < NN; i += TPB) xcol[i] = x[(size_t)i * FF + f];

    // own-feature p/q
    for (int r = wid; r < RR; r += 8) {
        float w  = W[((size_t)r * FF + f) * DD + lane];
        float pa = w * a[lane];
        float qa = w * a[DD + lane];
        #pragma unroll
        for (int o = 32; o > 0; o >>= 1) {
            pa += __shfl_down(pa, o);
            qa += __shfl_down(qa, o);
        }
        if (lane == 0) { p_sh[r] = pa; q_sh[r] = qa; }
    }
    __syncthreads();   // xcol + p_sh/q_sh ready

    // single pass: u = exp(v)*xd, s = sum(exp(v))
    float uvals[EPT];
    float s = 0.0f;
    #pragma unroll
    for (int k = 0; k < EPT; ++k) {
        float xs = xcol[siA[k]];
        float xd = xcol[diA[k]];
        float v = xs * p_sh[rA[k]] + xd * q_sh[rA[k]];
        v = v > 0.0f ? v : ALPHA * v;
        float ev = expf(v);
        uvals[k] = ev * xd;
        s += ev;
    }
    #pragma unroll
    for (int o = 32; o > 0; o >>= 1) s += __shfl_down(s, o);
    if (lane == 0) red_s[wid] = s;
    __syncthreads();
    float st = red_s[0];
    #pragma unroll
    for (int i = 1; i < 8; ++i) st += red_s[i];
    float inv = 1.0f / st;

    #pragma unroll
    for (int k = 0; k < EPT; ++k) {
        int e = tid + k * TPB;
        cbuf[(size_t)e * FF + f] = uvals[k] * inv;
    }
}

// K2: block = tile of 32 same-relation edges; 8 waves, wave = 4 edges.
//     tile_rel breaks the perm->rel->W dependent-load chain (W staging
//     starts after ONE load). Entire 64 KB W_r staged with 8-deep MLP
//     (8 float4/thread in flight), ONE barrier, then all compute
//     barrier-free. Guard tile_rel[t] < 0 -> empty tile.
__global__ __launch_bounds__(TPB) void k2_out(
    const float* __restrict__ W, const float* __restrict__ cbuf,
    const int* __restrict__ perm, const int* __restrict__ tile_rel,
    float* __restrict__ out) {

    const int t    = blockIdx.x;   // 0..75
    const int tid  = threadIdx.x;
    const int wid  = tid >> 6;
    const int lane = tid & 63;

    const int r = tile_rel[t];     // single scalar load
    if (r < 0) return;             // empty tile (block-uniform)

    __shared__ float Wl[FF * DD];  // 64 KB: full W_r
    __shared__ int   e_sh[TILE_E];

    const float* __restrict__ Wr = W + (size_t)r * FF * DD;

    // issue ALL W loads (8 float4/thread, independent -> 8-deep MLP);
    // e_sh load proceeds in parallel
    float4 wst[8];
    #pragma unroll
    for (int it = 0; it < 8; ++it) {
        int g = it * TPB + tid;            // float4 index 0..4095
        wst[it] = *(const float4*)&Wr[(size_t)g * 4];
    }
    if (tid < TILE_E) e_sh[tid] = perm[t * TILE_E + tid];

    #pragma unroll
    for (int it = 0; it < 8; ++it) {
        int g = it * TPB + tid;
        *(float4*)&Wl[(size_t)g * 4] = wst[it];
    }
    __syncthreads();               // ONE barrier; all compute below sync-free

    int eb[4];
    const float* ce[4];
    float4 acc[4];
    #pragma unroll
    for (int j = 0; j < 4; ++j) {
        eb[j]  = e_sh[wid * 4 + j];
        ce[j]  = cbuf + (size_t)(eb[j] >= 0 ? eb[j] : 0) * FF;
        acc[j] = make_float4(0.f, 0.f, 0.f, 0.f);
    }

    const int fg = lane >> 4;      // 0..3: f within a 4-group
    const int dq = lane & 15;      // 0..15: d-quad

    #pragma unroll
    for (int fc = 0; fc < FF / 32; ++fc) {
        #pragma unroll
        for (int i = 0; i < 8; ++i) {
            int gf = fc * 32 + i * 4 + fg;          // global f
            float4 w4 = *(const float4*)&Wl[gf * DD + dq * 4];
            #pragma unroll
            for (int j = 0; j < 4; ++j) {
                float c = ce[j][gf];                // broadcast/16 lanes
                acc[j].x = fmaf(c, w4.x, acc[j].x);
                acc[j].y = fmaf(c, w4.y, acc[j].y);
                acc[j].z = fmaf(c, w4.z, acc[j].z);
                acc[j].w = fmaf(c, w4.w, acc[j].w);
            }
        }
    }

    // per edge: sum the 4 f-groups (lanes l, l^16, l^32, l^48 share d-quad)
    #pragma unroll
    for (int j = 0; j < 4; ++j) {
        #pragma unroll
        for (int o = 16; o <= 32; o <<= 1) {
            acc[j].x += __shfl_xor(acc[j].x, o);
            acc[j].y += __shfl_xor(acc[j].y, o);
            acc[j].z += __shfl_xor(acc[j].z, o);
            acc[j].w += __shfl_xor(acc[j].w, o);
        }
        if (eb[j] >= 0 && fg == 0)
            *(float4*)&out[(size_t)eb[j] * DD + dq * 4] = acc[j];
    }
}

extern "C" void kernel_launch(void* const* d_in, const int* in_sizes, int n_in,
                              void* d_out, int out_size, void* d_ws, size_t ws_size,
                              hipStream_t stream) {
    const float* x  = (const float*)d_in[0];   // [N, F]
    const float* W  = (const float*)d_in[1];   // [R, F, D]
    const float* a  = (const float*)d_in[2];   // [2*D]
    const int* src  = (const int*)d_in[3];     // [E]
    const int* dst  = (const int*)d_in[4];     // [E]
    const int* rel  = (const int*)d_in[5];     // [E]
    float* out      = (float*)d_out;           // [E*D]

    char* wsb = (char*)d_ws;
    int*   perm     = (int*)wsb;
    int*   tile_rel = (int*)(wsb + 12288);
    float* cbuf     = (float*)(wsb + 16384);

    k1_coef<<<FF + 1, TPB, 0, stream>>>(x, W, a, src, dst, rel,
                                        cbuf, perm, tile_rel);
    k2_out<<<K2_GRID, TPB, 0, stream>>>(W, cbuf, perm, tile_rel, out);
}

// Round 19
// 25.470 us; speedup vs baseline: 3.9734x; 3.9734x over previous
//
#include <hip/hip_runtime.h>
#include <hip/hip_bf16.h>

// Problem constants (match reference)
#define NN 1024
#define FF 256
#define DD 64
#define RR 11
#define EE 2048
#define ALPHA 0.2f
#define TPB 512
#define EPT (EE / TPB)          // 4 edges per thread in K1
#define TILE_E 32               // edges per K2 tile (same relation)
#define PERM_CAP 2432           // >= 2048 + 11*31, = 76*32
#define K2_GRID (PERM_CAP / TILE_E)  // 76

// ws layout (bytes):
//   0     : int perm[PERM_CAP]    (9728 B)
//   12288 : int tile_rel[K2_GRID] (304 B)  relation per tile, -1 = empty
//   16384 : float cbuf[EE*FF]     (2 MB, e-major: cbuf[e*FF+f])

// K1 (R17-proven): blocks 0..255 own feature f=(b&7)*32+(b>>3) [XCD-grouped].
//     Stage x[:,f] in LDS; p/q wave-dots; single-pass softmax (|v|<~2);
//     c[e,f]=exp(v)*xd/sum (e-major). Block 256: relation counting-sort into
//     32-padded buckets + tile_rel table (concurrent with feature blocks).
__global__ __launch_bounds__(TPB) void k1_coef(
    const float* __restrict__ x, const float* __restrict__ W,
    const float* __restrict__ a, const int* __restrict__ src,
    const int* __restrict__ dst, const int* __restrict__ rel,
    float* __restrict__ cbuf, int* __restrict__ perm,
    int* __restrict__ tile_rel) {

    const int b    = blockIdx.x;   // 0..256
    const int tid  = threadIdx.x;  // 0..511
    const int wid  = tid >> 6;     // 0..7
    const int lane = tid & 63;

    __shared__ int hist[16], base_sh[16], off_sh[16];

    if (b == FF) {
        // dedicated sort block
        if (tid < 16) hist[tid] = 0;
        __syncthreads();
        for (int e = tid; e < EE; e += TPB) atomicAdd(&hist[rel[e]], 1);
        __syncthreads();
        if (tid == 0) {
            int acc = 0;
            for (int r = 0; r < RR; ++r) {
                base_sh[r] = acc;
                off_sh[r] = acc;
                acc += (hist[r] + TILE_E - 1) & ~(TILE_E - 1);
            }
            int r = 0;
            for (int t = 0; t < K2_GRID; ++t) {
                while (r < RR && t * TILE_E >=
                       base_sh[r] + ((hist[r] + TILE_E - 1) & ~(TILE_E - 1)))
                    ++r;
                tile_rel[t] = (r < RR &&
                               t * TILE_E < base_sh[r] +
                               ((hist[r] + TILE_E - 1) & ~(TILE_E - 1)))
                              ? r : -1;
            }
        }
        __syncthreads();
        for (int i = tid; i < PERM_CAP; i += TPB) perm[i] = -1;
        __syncthreads();
        for (int e = tid; e < EE; e += TPB) {
            int pos = atomicAdd(&off_sh[rel[e]], 1);
            perm[pos] = e;
        }
        return;
    }

    const int f = ((b & 7) << 5) | (b >> 3);   // XCD-grouped feature

    __shared__ float xcol[NN];     // 4 KB: x[:, f]
    __shared__ float p_sh[RR], q_sh[RR];
    __shared__ float red_s[8];

    // stage column f of x (lines L2-shared within this XCD)
    for (int i = tid; i < NN; i += TPB) xcol[i] = x[(size_t)i * FF + f];

    // own-feature p/q
    for (int r = wid; r < RR; r += 8) {
        float w  = W[((size_t)r * FF + f) * DD + lane];
        float pa = w * a[lane];
        float qa = w * a[DD + lane];
        #pragma unroll
        for (int o = 32; o > 0; o >>= 1) {
            pa += __shfl_down(pa, o);
            qa += __shfl_down(qa, o);
        }
        if (lane == 0) { p_sh[r] = pa; q_sh[r] = qa; }
    }
    __syncthreads();   // xcol + p_sh/q_sh ready

    // single pass: u = exp(v)*xd, s = sum(exp(v))
    float uvals[EPT];
    float s = 0.0f;
    #pragma unroll
    for (int k = 0; k < EPT; ++k) {
        int e = tid + k * TPB;
        float xs = xcol[src[e]];
        float xd = xcol[dst[e]];
        int r = rel[e];
        float v = xs * p_sh[r] + xd * q_sh[r];
        v = v > 0.0f ? v : ALPHA * v;
        float ev = expf(v);
        uvals[k] = ev * xd;
        s += ev;
    }
    #pragma unroll
    for (int o = 32; o > 0; o >>= 1) s += __shfl_down(s, o);
    if (lane == 0) red_s[wid] = s;
    __syncthreads();
    float st = red_s[0];
    #pragma unroll
    for (int i = 1; i < 8; ++i) st += red_s[i];
    float inv = 1.0f / st;

    #pragma unroll
    for (int k = 0; k < EPT; ++k) {
        int e = tid + k * TPB;
        cbuf[(size_t)e * FF + f] = uvals[k] * inv;
    }
}

// K2: block = tile of 32 same-relation edges; 8 waves, wave = 4 edges.
//     tile_rel -> single scalar load starts W staging immediately.
//     NEW: the tile's 32 cbuf rows (32 KB) staged into LDS with coalesced
//     float4 loads (depth-4 MLP, no e_sh barrier dependency) -- the inner
//     loop's 256 scalar global broadcasts/thread become LDS reads.
//     W via R17-proven ping-pong 8 KB chunks (one barrier per chunk).
__global__ __launch_bounds__(TPB) void k2_out(
    const float* __restrict__ W, const float* __restrict__ cbuf,
    const int* __restrict__ perm, const int* __restrict__ tile_rel,
    float* __restrict__ out) {

    const int t    = blockIdx.x;   // 0..75
    const int tid  = threadIdx.x;
    const int wid  = tid >> 6;
    const int lane = tid & 63;

    const int r = tile_rel[t];     // single scalar load
    if (r < 0) return;             // empty tile (block-uniform)

    __shared__ float Cl[TILE_E][FF];   // 32 KB: tile's cbuf rows
    __shared__ float Wl[2][32 * DD];   // 2 x 8 KB ping-pong W chunks
    __shared__ int   eb_sh[TILE_E];

    const float* __restrict__ Wr = W + (size_t)r * FF * DD;

    // --- cbuf stage: row = tid>>4 (16 threads/row), 4 float4s per thread.
    //     Edge index via direct global load (broadcast within 16 threads).
    {
        const int row = tid >> 4;          // 0..31
        const int c4  = tid & 15;          // float4 col base
        int er = perm[t * TILE_E + row];
        if ((tid & 15) == 0) eb_sh[row] = er;
        const float* crow = cbuf + (size_t)(er >= 0 ? er : 0) * FF;
        float4 cst[4];
        #pragma unroll
        for (int i = 0; i < 4; ++i)        // 4 independent 16B loads in flight
            cst[i] = *(const float4*)&crow[(c4 + i * 16) * 4];
        #pragma unroll
        for (int i = 0; i < 4; ++i)
            *(float4*)&Cl[row][(c4 + i * 16) * 4] = cst[i];
    }

    // --- W chunk 0 stage (issues in parallel with the cbuf loads above)
    const int srow = tid >> 4;     // 0..31: staging row
    const int scol = tid & 15;     // 0..15: staging float4 col
    *(float4*)&Wl[0][srow * DD + scol * 4] =
        *(const float4*)&Wr[(size_t)srow * DD + scol * 4];
    __syncthreads();

    int eb[4];
    float4 acc[4];
    #pragma unroll
    for (int j = 0; j < 4; ++j) {
        eb[j]  = eb_sh[wid * 4 + j];
        acc[j] = make_float4(0.f, 0.f, 0.f, 0.f);
    }

    const int fg = lane >> 4;      // 0..3: f within a 4-group
    const int dq = lane & 15;      // 0..15: d-quad

    #pragma unroll
    for (int fc = 0; fc < FF / 32; ++fc) {   // 8 chunks of 32 features
        float4 nxt;
        if (fc < FF / 32 - 1)                // next chunk load hides under FMAs
            nxt = *(const float4*)
                &Wr[(size_t)((fc + 1) * 32 + srow) * DD + scol * 4];

        const float* Wc = Wl[fc & 1];
        #pragma unroll
        for (int i = 0; i < 8; ++i) {
            int lf = i * 4 + fg;                        // local f 0..31
            float4 w4 = *(const float4*)&Wc[lf * DD + dq * 4];
            int gf = fc * 32 + lf;
            #pragma unroll
            for (int j = 0; j < 4; ++j) {
                float c = Cl[wid * 4 + j][gf];          // LDS broadcast/16 lanes
                acc[j].x = fmaf(c, w4.x, acc[j].x);
                acc[j].y = fmaf(c, w4.y, acc[j].y);
                acc[j].z = fmaf(c, w4.z, acc[j].z);
                acc[j].w = fmaf(c, w4.w, acc[j].w);
            }
        }

        if (fc < FF / 32 - 1) {              // write other buffer, one barrier
            *(float4*)&Wl[(fc + 1) & 1][srow * DD + scol * 4] = nxt;
            __syncthreads();
        }
    }

    // per edge: sum the 4 f-groups (lanes l, l^16, l^32, l^48 share d-quad)
    #pragma unroll
    for (int j = 0; j < 4; ++j) {
        #pragma unroll
        for (int o = 16; o <= 32; o <<= 1) {
            acc[j].x += __shfl_xor(acc[j].x, o);
            acc[j].y += __shfl_xor(acc[j].y, o);
            acc[j].z += __shfl_xor(acc[j].z, o);
            acc[j].w += __shfl_xor(acc[j].w, o);
        }
        if (eb[j] >= 0 && fg == 0)
            *(float4*)&out[(size_t)eb[j] * DD + dq * 4] = acc[j];
    }
}

extern "C" void kernel_launch(void* const* d_in, const int* in_sizes, int n_in,
                              void* d_out, int out_size, void* d_ws, size_t ws_size,
                              hipStream_t stream) {
    const float* x  = (const float*)d_in[0];   // [N, F]
    const float* W  = (const float*)d_in[1];   // [R, F, D]
    const float* a  = (const float*)d_in[2];   // [2*D]
    const int* src  = (const int*)d_in[3];     // [E]
    const int* dst  = (const int*)d_in[4];     // [E]
    const int* rel  = (const int*)d_in[5];     // [E]
    float* out      = (float*)d_out;           // [E*D]

    char* wsb = (char*)d_ws;
    int*   perm     = (int*)wsb;
    int*   tile_rel = (int*)(wsb + 12288);
    float* cbuf     = (float*)(wsb + 16384);

    k1_coef<<<FF + 1, TPB, 0, stream>>>(x, W, a, src, dst, rel,
                                        cbuf, perm, tile_rel);
    k2_out<<<K2_GRID, TPB, 0, stream>>>(W, cbuf, perm, tile_rel, out);
}